// Round 2
// baseline (77.406 us; speedup 1.0000x reference)
//
#include <hip/hip_runtime.h>
#include <math.h>

#define BB 2
#define SS 512
#define HH 256
#define AA 128
#define CH 4
#define NCH (SS / CH)      // 128 chunks per batch
#define NBLK (BB * NCH)    // 256 blocks == #CUs
#define NT 512             // 8 waves/block -> 2 waves/SIMD

typedef float f4_t __attribute__((ext_vector_type(4)));

// Monotone ticket counter: each launch adds exactly NBLK, so generation
// arithmetic works across unlimited launches / graph replays / rocprof passes.
__device__ unsigned g_tick = 0;

// One fused kernel. Block (b,c) owns rows j0..j0+3 (both as E/C producer in
// phase 1 and as output rows in phase 2, so the x tile stays in LDS).
__global__ __launch_bounds__(NT, 2)
void k_fused(const float* __restrict__ x,
             const int* __restrict__ am,
             const float* __restrict__ w_a,
             const float* __restrict__ query,
             float* __restrict__ Ews,
             float* __restrict__ Cws,
             float* __restrict__ dout,
             float* __restrict__ aout) {
    const int blk = blockIdx.x;
    const int b   = blk >> 7;
    const int c   = blk & 127;
    const int j0  = c * CH;            // == output row base i0
    const int tid = threadIdx.x;

    __shared__ float xs[CH][HH];        // 4 KB, lives across both phases
    __shared__ float pred[16][CH][AA];  // 32 KB matmul partials
    __shared__ float redr[CH][2];
    __shared__ float Wl[CH];
    __shared__ float Es[SS];            // 2 KB
    __shared__ float Ws[SS];            // 2 KB
    __shared__ float cpar[2][HH];       // 2 KB
    __shared__ float Pinv[CH];
    __shared__ float red8[8];
    __shared__ int   amis[CH];

    // ---------------- phase 1: stage 4 x-rows (4 KB), coalesced ----------------
    {
        const float2* src = (const float2*)(x + (size_t)(b * SS + j0) * HH);
        ((float2*)&xs[0][0])[tid] = src[tid];
    }
    __syncthreads();

    // ---------------- phase 1: t[r][a] = sum_h xs[r][h] * w_a[h][a] ------------
    // thread = (a-quad q, h-slot hs): 4 a's x 16 h's. 16 independent float4
    // w_a loads per thread -> deep MLP instead of 32 serialized scalar batches.
    const int q  = tid & 31;
    const int hs = tid >> 5;           // 0..15
    const int h0 = hs << 4;
    float4 acc0 = make_float4(0.f, 0.f, 0.f, 0.f);
    float4 acc1 = acc0, acc2 = acc0, acc3 = acc0;
    const float4* w4 = (const float4*)w_a;   // [HH][AA/4]

#define ROWFMA(ACC, R)                                                          \
    {                                                                           \
        const float4 xv = *(const float4*)&xs[R][h];                            \
        ACC.x = fmaf(xv.x, wa.x, fmaf(xv.y, wb.x, fmaf(xv.z, wc.x, fmaf(xv.w, wd.x, ACC.x)))); \
        ACC.y = fmaf(xv.x, wa.y, fmaf(xv.y, wb.y, fmaf(xv.z, wc.y, fmaf(xv.w, wd.y, ACC.y)))); \
        ACC.z = fmaf(xv.x, wa.z, fmaf(xv.y, wb.z, fmaf(xv.z, wc.z, fmaf(xv.w, wd.z, ACC.z)))); \
        ACC.w = fmaf(xv.x, wa.w, fmaf(xv.y, wb.w, fmaf(xv.z, wc.w, fmaf(xv.w, wd.w, ACC.w)))); \
    }

#pragma unroll
    for (int hh = 0; hh < 16; hh += 4) {
        const int h = h0 + hh;
        const float4 wa = w4[(h + 0) * (AA / 4) + q];
        const float4 wb = w4[(h + 1) * (AA / 4) + q];
        const float4 wc = w4[(h + 2) * (AA / 4) + q];
        const float4 wd = w4[(h + 3) * (AA / 4) + q];
        ROWFMA(acc0, 0)
        ROWFMA(acc1, 1)
        ROWFMA(acc2, 2)
        ROWFMA(acc3, 3)
    }
#undef ROWFMA

    *(float4*)&pred[hs][0][q << 2] = acc0;
    *(float4*)&pred[hs][1][q << 2] = acc1;
    *(float4*)&pred[hs][2][q << 2] = acc2;
    *(float4*)&pred[hs][3][q << 2] = acc3;
    __syncthreads();

    // reduce over 16 h-slots, tanh, dot with query, reduce over a (2 waves/row)
    {
        const int r = tid >> 7;        // 0..3
        const int a = tid & 127;
        float s = 0.f;
#pragma unroll
        for (int t = 0; t < 16; ++t) s += pred[t][r][a];
        float v = tanhf(s) * query[a];
#pragma unroll
        for (int off = 32; off; off >>= 1) v += __shfl_down(v, off, 64);
        if ((tid & 63) == 0) redr[r][(tid >> 6) & 1] = v;
    }
    if (tid < CH) amis[tid] = am[b * SS + j0 + tid];
    __syncthreads();
    if (tid < CH) {
        const float t = redr[tid][0] + redr[tid][1];
        const float e = expf(t);       // unshifted: |t| ~ 9 << 88 for this input
        Wl[tid] = amis[tid] ? e : 0.f;
        Ews[b * SS + j0 + tid] = e;
    }
    __syncthreads();

    // chunk partial C[h] = sum_r W[r] * x[r][h]
    if (tid < HH) {
        const float cacc = fmaf(Wl[0], xs[0][tid],
                           fmaf(Wl[1], xs[1][tid],
                           fmaf(Wl[2], xs[2][tid],
                                Wl[3] * xs[3][tid])));
        Cws[(size_t)(b * NCH + c) * HH + tid] = cacc;
    }
    __syncthreads();

    // ---------------- grid barrier (ticket; agent-scope acq/rel) ---------------
    if (tid == 0) {
        const unsigned old =
            __hip_atomic_fetch_add(&g_tick, 1u, __ATOMIC_RELEASE, __HIP_MEMORY_SCOPE_AGENT);
        const unsigned target = (old / NBLK + 1u) * NBLK;
        while (__hip_atomic_load(&g_tick, __ATOMIC_RELAXED, __HIP_MEMORY_SCOPE_AGENT) < target)
            __builtin_amdgcn_s_sleep(2);
        (void)__hip_atomic_load(&g_tick, __ATOMIC_ACQUIRE, __HIP_MEMORY_SCOPE_AGENT);
    }
    __syncthreads();

    // ---------------- phase 2: outputs for rows i0 = j0 ------------------------
    // load full E row for this batch (exactly 512 = NT loads) + masks; P_base
    {
        const float e = Ews[b * SS + tid];
        const int  m  = am[b * SS + tid];
        Es[tid] = e;
        Ws[tid] = m ? e : 0.f;
        float p = (tid <= j0) ? e : 0.f;
#pragma unroll
        for (int off = 32; off; off >>= 1) p += __shfl_down(p, off, 64);
        if ((tid & 63) == 0) red8[tid >> 6] = p;
    }
    __syncthreads();
    if (tid == 0) {
        const float P0 = ((red8[0] + red8[1]) + (red8[2] + red8[3]))
                       + ((red8[4] + red8[5]) + (red8[6] + red8[7]));
        const float P1 = P0 + Es[j0 + 1];
        const float P2 = P1 + Es[j0 + 2];
        const float P3 = P2 + Es[j0 + 3];
        Pinv[0] = 1.f / P0; Pinv[1] = 1.f / P1;
        Pinv[2] = 1.f / P2; Pinv[3] = 1.f / P3;
    }
    __syncthreads();

    // d rows: exactly one float4 store per thread (nontemporal, native vec type)
    {
        const int   r  = tid >> 7;
        const int   jc = (tid & 127) << 2;
        const int   i  = j0 + r;
        const float pv = Pinv[r];
        const bool  on = amis[r] != 0;
        const float4 wv = *(const float4*)&Ws[jc];
        f4_t o;
        o.x = (on && jc + 0 <= i) ? wv.x * pv : 0.f;
        o.y = (on && jc + 1 <= i) ? wv.y * pv : 0.f;
        o.z = (on && jc + 2 <= i) ? wv.z * pv : 0.f;
        o.w = (on && jc + 3 <= i) ? wv.w * pv : 0.f;
        __builtin_nontemporal_store(o, (f4_t*)&dout[(size_t)(b * SS + i) * SS + jc]);
    }

    // a rows: prefix over C chunks, dependency chain split 2-way across threads
    {
        const int g = tid >> 8;        // 0/1
        const int h = tid & 255;
        const int nfull = c;           // chunks strictly below i0
        const float* Cb = Cws + (size_t)b * NCH * HH + h;
        float s0 = 0.f, s1 = 0.f, s2 = 0.f, s3 = 0.f;
        int cc = g;
        for (; cc + 7 <= nfull; cc += 8) {
            s0 += Cb[(size_t)(cc + 0) * HH];
            s1 += Cb[(size_t)(cc + 2) * HH];
            s2 += Cb[(size_t)(cc + 4) * HH];
            s3 += Cb[(size_t)(cc + 6) * HH];
        }
        for (; cc < nfull; cc += 2) s0 += Cb[(size_t)cc * HH];
        cpar[g][h] = (s0 + s1) + (s2 + s3);
    }
    __syncthreads();
    if (tid < HH) {
        const int   h    = tid;
        const float base = cpar[0][h] + cpar[1][h];
        const float a0 = fmaf(Ws[j0 + 0], xs[0][h], base);
        const float a1 = fmaf(Ws[j0 + 1], xs[1][h], a0);
        const float a2 = fmaf(Ws[j0 + 2], xs[2][h], a1);
        const float a3 = fmaf(Ws[j0 + 3], xs[3][h], a2);
        const size_t arow = (size_t)(b * SS + j0) * HH + h;
        __builtin_nontemporal_store(amis[0] ? a0 * Pinv[0] : 0.f, &aout[arow + 0 * HH]);
        __builtin_nontemporal_store(amis[1] ? a1 * Pinv[1] : 0.f, &aout[arow + 1 * HH]);
        __builtin_nontemporal_store(amis[2] ? a2 * Pinv[2] : 0.f, &aout[arow + 2 * HH]);
        __builtin_nontemporal_store(amis[3] ? a3 * Pinv[3] : 0.f, &aout[arow + 3 * HH]);
    }
}

// ---------------------------------------------------------------------------
extern "C" void kernel_launch(void* const* d_in, const int* in_sizes, int n_in,
                              void* d_out, int out_size, void* d_ws, size_t ws_size,
                              hipStream_t stream) {
    const float* x     = (const float*)d_in[0];
    const int*   am    = (const int*)d_in[1];
    const float* w_a   = (const float*)d_in[2];
    const float* query = (const float*)d_in[3];

    float* a_out  = (float*)d_out;                   // B*S*H
    float* d_outp = a_out + (size_t)BB * SS * HH;    // B*S*S

    float* Ews = (float*)d_ws;                       // B*S floats
    float* Cws = Ews + BB * SS;                      // B*NCH*H floats (256 KB)

    k_fused<<<NBLK, NT, 0, stream>>>(x, am, w_a, query, Ews, Cws, d_outp, a_out);
}

// Round 3
// 72.858 us; speedup vs baseline: 1.0624x; 1.0624x over previous
//
#include <hip/hip_runtime.h>
#include <math.h>

#define BB 2
#define SS 512
#define HH 256
#define AA 128
#define CH 4
#define NCH (SS / CH)      // 128 chunks per batch
#define NBLK (BB * NCH)    // 256 blocks for k1
#define NT1 512            // k1: 8 waves/block

typedef float f4_t __attribute__((ext_vector_type(4)));

// ---------------------------------------------------------------------------
// Kernel 1: per 4-row chunk (256 blocks x 512 thr):
//   E[j]  = exp( sum_a q[a] * tanh( sum_h x[j,h] * w_a[h,a] ) )
//   C[c,h]= sum_{r<4} (am? E:0)[j0+r] * x[j0+r,h]
// Each block reads w_a exactly once as float4 (16 independent loads/thread).
// ---------------------------------------------------------------------------
__global__ __launch_bounds__(NT1, 2)
void k_E(const float* __restrict__ x,
         const int* __restrict__ am,
         const float* __restrict__ w_a,
         const float* __restrict__ query,
         float* __restrict__ Ews,
         float* __restrict__ Cws) {
    const int blk = blockIdx.x;
    const int b   = blk >> 7;
    const int c   = blk & 127;
    const int j0  = c * CH;
    const int tid = threadIdx.x;

    __shared__ float xs[CH][HH];        // 4 KB
    __shared__ float pred[16][CH][AA];  // 32 KB matmul partials
    __shared__ float redr[CH][2];
    __shared__ float Wl[CH];
    __shared__ int   amis[CH];

    // stage 4 x-rows (4 KB), coalesced float2
    {
        const float2* src = (const float2*)(x + (size_t)(b * SS + j0) * HH);
        ((float2*)&xs[0][0])[tid] = src[tid];
    }
    __syncthreads();

    // thread = (a-quad q in 0..31, h-slot hs in 0..15): 16 float4 w loads, MLP-16
    const int q  = tid & 31;
    const int hs = tid >> 5;
    const int h0 = hs << 4;
    float4 acc0 = make_float4(0.f, 0.f, 0.f, 0.f);
    float4 acc1 = acc0, acc2 = acc0, acc3 = acc0;
    const float4* w4 = (const float4*)w_a;   // [HH][AA/4]

#define ROWFMA(ACC, R)                                                          \
    {                                                                           \
        const float4 xv = *(const float4*)&xs[R][h];                            \
        ACC.x = fmaf(xv.x, wa.x, fmaf(xv.y, wb.x, fmaf(xv.z, wc.x, fmaf(xv.w, wd.x, ACC.x)))); \
        ACC.y = fmaf(xv.x, wa.y, fmaf(xv.y, wb.y, fmaf(xv.z, wc.y, fmaf(xv.w, wd.y, ACC.y)))); \
        ACC.z = fmaf(xv.x, wa.z, fmaf(xv.y, wb.z, fmaf(xv.z, wc.z, fmaf(xv.w, wd.z, ACC.z)))); \
        ACC.w = fmaf(xv.x, wa.w, fmaf(xv.y, wb.w, fmaf(xv.z, wc.w, fmaf(xv.w, wd.w, ACC.w)))); \
    }

#pragma unroll
    for (int hh = 0; hh < 16; hh += 4) {
        const int h = h0 + hh;
        const float4 wa = w4[(h + 0) * (AA / 4) + q];
        const float4 wb = w4[(h + 1) * (AA / 4) + q];
        const float4 wc = w4[(h + 2) * (AA / 4) + q];
        const float4 wd = w4[(h + 3) * (AA / 4) + q];
        ROWFMA(acc0, 0)
        ROWFMA(acc1, 1)
        ROWFMA(acc2, 2)
        ROWFMA(acc3, 3)
    }
#undef ROWFMA

    *(float4*)&pred[hs][0][q << 2] = acc0;
    *(float4*)&pred[hs][1][q << 2] = acc1;
    *(float4*)&pred[hs][2][q << 2] = acc2;
    *(float4*)&pred[hs][3][q << 2] = acc3;
    __syncthreads();

    // reduce 16 h-slots, tanh, dot with query, wave-reduce over a
    {
        const int r = tid >> 7;        // 0..3
        const int a = tid & 127;
        float s = 0.f;
#pragma unroll
        for (int t = 0; t < 16; ++t) s += pred[t][r][a];
        float v = tanhf(s) * query[a];
#pragma unroll
        for (int off = 32; off; off >>= 1) v += __shfl_down(v, off, 64);
        if ((tid & 63) == 0) redr[r][(tid >> 6) & 1] = v;
    }
    if (tid < CH) amis[tid] = am[b * SS + j0 + tid];
    __syncthreads();
    if (tid < CH) {
        const float t = redr[tid][0] + redr[tid][1];
        const float e = expf(t);       // unshifted: |t| <= ~9 for this problem
        Wl[tid] = amis[tid] ? e : 0.f;
        Ews[b * SS + j0 + tid] = e;
    }
    __syncthreads();

    if (tid < HH) {
        const float cacc = fmaf(Wl[0], xs[0][tid],
                           fmaf(Wl[1], xs[1][tid],
                           fmaf(Wl[2], xs[2][tid],
                                Wl[3] * xs[3][tid])));
        Cws[(size_t)(b * NCH + c) * HH + tid] = cacc;
    }
}

// ---------------------------------------------------------------------------
// Kernel 2: 512 blocks x 256 thr, 2 output rows per block (2 blocks/CU):
//   P_i = sum_{j<=i} E[j];  d[i,j] = (j<=i && am_i && am_j) ? E[j]/P_i : 0
//   a[i,h] = am_i/P_i * ( sum_{chunks below} C[cc][h] + incremental rows )
// Prefix loop: 8 independent accumulators -> 8 loads in flight, <=16 rounds.
// ---------------------------------------------------------------------------
__global__ __launch_bounds__(256, 4)
void k_O(const float* __restrict__ Ews,
         const float* __restrict__ Cws,
         const int* __restrict__ am,
         const float* __restrict__ x,
         float* __restrict__ dout,
         float* __restrict__ aout) {
    const int blk = blockIdx.x;            // 0..511
    const int b   = blk >> 8;
    const int i0  = (blk & 255) << 1;      // even row base, 2 rows per block
    const int tid = threadIdx.x;           // 0..255
    const int lane = tid & 63;

    __shared__ float Es[SS];
    __shared__ float Ws[SS];
    __shared__ float red[4];
    __shared__ float Pinv[2];
    __shared__ int   amis[2];

    const float e0 = Ews[b * SS + tid];
    const float e1 = Ews[b * SS + tid + 256];
    const int  m0  = am[b * SS + tid];
    const int  m1  = am[b * SS + tid + 256];
    Es[tid] = e0;             Es[tid + 256] = e1;
    Ws[tid] = m0 ? e0 : 0.f;  Ws[tid + 256] = m1 ? e1 : 0.f;

    // P0 = sum_{j<=i0} E[j]
    float p = ((tid <= i0) ? e0 : 0.f) + ((tid + 256 <= i0) ? e1 : 0.f);
#pragma unroll
    for (int off = 32; off; off >>= 1) p += __shfl_down(p, off, 64);
    if (lane == 0) red[tid >> 6] = p;
    if (tid < 2) amis[tid] = am[b * SS + i0 + tid];
    __syncthreads();
    if (tid == 0) {
        const float P0 = (red[0] + red[1]) + (red[2] + red[3]);
        const float P1 = P0 + Es[i0 + 1];
        Pinv[0] = 1.f / P0;
        Pinv[1] = 1.f / P1;
    }
    __syncthreads();

    // ---- d rows: one float4 store per thread
    {
        const int   r  = tid >> 7;          // 0..1
        const int   jc = (tid & 127) << 2;
        const int   i  = i0 + r;
        const float pv = Pinv[r];
        const bool  on = amis[r] != 0;
        const float4 wv = *(const float4*)&Ws[jc];
        f4_t o;
        o.x = (on && jc + 0 <= i) ? wv.x * pv : 0.f;
        o.y = (on && jc + 1 <= i) ? wv.y * pv : 0.f;
        o.z = (on && jc + 2 <= i) ? wv.z * pv : 0.f;
        o.w = (on && jc + 3 <= i) ? wv.w * pv : 0.f;
        __builtin_nontemporal_store(o, (f4_t*)&dout[(size_t)(b * SS + i) * SS + jc]);
    }

    // ---- a rows: chunk prefix with 8-way MLP, then 2-4 incremental rows
    {
        const int h     = tid;                  // 256 threads == HH
        const int nfull = i0 >> 2;              // chunks strictly below i0
        const int lo    = i0 & 3;               // 0 or 2 leftover rows
        const float* Cb = Cws + (size_t)b * NCH * HH + h;

        float s0 = 0.f, s1 = 0.f, s2 = 0.f, s3 = 0.f;
        float s4 = 0.f, s5 = 0.f, s6 = 0.f, s7 = 0.f;
        int cc = 0;
        for (; cc + 8 <= nfull; cc += 8) {
            s0 += Cb[(size_t)(cc + 0) * HH];
            s1 += Cb[(size_t)(cc + 1) * HH];
            s2 += Cb[(size_t)(cc + 2) * HH];
            s3 += Cb[(size_t)(cc + 3) * HH];
            s4 += Cb[(size_t)(cc + 4) * HH];
            s5 += Cb[(size_t)(cc + 5) * HH];
            s6 += Cb[(size_t)(cc + 6) * HH];
            s7 += Cb[(size_t)(cc + 7) * HH];
        }
        for (; cc < nfull; ++cc) s0 += Cb[(size_t)cc * HH];
        float acc = ((s0 + s1) + (s2 + s3)) + ((s4 + s5) + (s6 + s7));

        const int jbase = nfull << 2;           // first row not covered by chunks
        const float* xb = x + ((size_t)b * SS + jbase) * HH + h;
        float av0, av1;
        if (lo) {   // block-uniform branch
            acc = fmaf(Ws[jbase + 0], xb[0 * HH], acc);
            acc = fmaf(Ws[jbase + 1], xb[1 * HH], acc);
            av0 = fmaf(Ws[i0 + 0],    xb[2 * HH], acc);
            av1 = fmaf(Ws[i0 + 1],    xb[3 * HH], av0);
        } else {
            av0 = fmaf(Ws[i0 + 0],    xb[0 * HH], acc);
            av1 = fmaf(Ws[i0 + 1],    xb[1 * HH], av0);
        }

        const size_t arow = (size_t)(b * SS + i0) * HH + h;
        __builtin_nontemporal_store(amis[0] ? av0 * Pinv[0] : 0.f, &aout[arow + 0 * HH]);
        __builtin_nontemporal_store(amis[1] ? av1 * Pinv[1] : 0.f, &aout[arow + 1 * HH]);
    }
}

// ---------------------------------------------------------------------------
extern "C" void kernel_launch(void* const* d_in, const int* in_sizes, int n_in,
                              void* d_out, int out_size, void* d_ws, size_t ws_size,
                              hipStream_t stream) {
    const float* x     = (const float*)d_in[0];
    const int*   am    = (const int*)d_in[1];
    const float* w_a   = (const float*)d_in[2];
    const float* query = (const float*)d_in[3];

    float* a_out  = (float*)d_out;                   // B*S*H
    float* d_outp = a_out + (size_t)BB * SS * HH;    // B*S*S

    float* Ews = (float*)d_ws;                       // B*S floats
    float* Cws = Ews + BB * SS;                      // B*NCH*H floats (256 KB)

    k_E<<<NBLK,       NT1, 0, stream>>>(x, am, w_a, query, Ews, Cws);
    k_O<<<BB * SS / 2, 256, 0, stream>>>(Ews, Cws, am, x, d_outp, a_out);
}

// Round 4
// 69.899 us; speedup vs baseline: 1.1074x; 1.0423x over previous
//
#include <hip/hip_runtime.h>
#include <math.h>

#define BB 2
#define SS 512
#define HH 256
#define AA 128
#define CH 4
#define NCH (SS / CH)      // 128 chunks per batch
#define NBLK (BB * NCH)    // 256 blocks for k1
#define NT1 512            // k1: 8 waves/block

typedef float f4_t __attribute__((ext_vector_type(4)));

// ---------------------------------------------------------------------------
// Kernel 1: per 4-row chunk (256 blocks x 512 thr):
//   E[j]  = exp( sum_a q[a] * tanh( sum_h x[j,h] * w_a[h,a] ) )
//   C[c,h]= sum_{r<4} (am? E:0)[j0+r] * x[j0+r,h]
// Each block reads w_a exactly once as float4 (16 independent loads/thread).
// ---------------------------------------------------------------------------
__global__ __launch_bounds__(NT1, 2)
void k_E(const float* __restrict__ x,
         const int* __restrict__ am,
         const float* __restrict__ w_a,
         const float* __restrict__ query,
         float* __restrict__ Ews,
         float* __restrict__ Cws) {
    const int blk = blockIdx.x;
    const int b   = blk >> 7;
    const int c   = blk & 127;
    const int j0  = c * CH;
    const int tid = threadIdx.x;

    __shared__ float xs[CH][HH];        // 4 KB
    __shared__ float pred[16][CH][AA];  // 32 KB matmul partials
    __shared__ float redr[CH][2];
    __shared__ float Wl[CH];
    __shared__ int   amis[CH];

    // stage 4 x-rows (4 KB), coalesced float2
    {
        const float2* src = (const float2*)(x + (size_t)(b * SS + j0) * HH);
        ((float2*)&xs[0][0])[tid] = src[tid];
    }
    __syncthreads();

    // thread = (a-quad q in 0..31, h-slot hs in 0..15): 16 float4 w loads, MLP-16
    const int q  = tid & 31;
    const int hs = tid >> 5;
    const int h0 = hs << 4;
    float4 acc0 = make_float4(0.f, 0.f, 0.f, 0.f);
    float4 acc1 = acc0, acc2 = acc0, acc3 = acc0;
    const float4* w4 = (const float4*)w_a;   // [HH][AA/4]

#define ROWFMA(ACC, R)                                                          \
    {                                                                           \
        const float4 xv = *(const float4*)&xs[R][h];                            \
        ACC.x = fmaf(xv.x, wa.x, fmaf(xv.y, wb.x, fmaf(xv.z, wc.x, fmaf(xv.w, wd.x, ACC.x)))); \
        ACC.y = fmaf(xv.x, wa.y, fmaf(xv.y, wb.y, fmaf(xv.z, wc.y, fmaf(xv.w, wd.y, ACC.y)))); \
        ACC.z = fmaf(xv.x, wa.z, fmaf(xv.y, wb.z, fmaf(xv.z, wc.z, fmaf(xv.w, wd.z, ACC.z)))); \
        ACC.w = fmaf(xv.x, wa.w, fmaf(xv.y, wb.w, fmaf(xv.z, wc.w, fmaf(xv.w, wd.w, ACC.w)))); \
    }

#pragma unroll
    for (int hh = 0; hh < 16; hh += 4) {
        const int h = h0 + hh;
        const float4 wa = w4[(h + 0) * (AA / 4) + q];
        const float4 wb = w4[(h + 1) * (AA / 4) + q];
        const float4 wc = w4[(h + 2) * (AA / 4) + q];
        const float4 wd = w4[(h + 3) * (AA / 4) + q];
        ROWFMA(acc0, 0)
        ROWFMA(acc1, 1)
        ROWFMA(acc2, 2)
        ROWFMA(acc3, 3)
    }
#undef ROWFMA

    *(float4*)&pred[hs][0][q << 2] = acc0;
    *(float4*)&pred[hs][1][q << 2] = acc1;
    *(float4*)&pred[hs][2][q << 2] = acc2;
    *(float4*)&pred[hs][3][q << 2] = acc3;
    __syncthreads();

    // reduce 16 h-slots, tanh, dot with query, wave-reduce over a
    {
        const int r = tid >> 7;        // 0..3
        const int a = tid & 127;
        float s = 0.f;
#pragma unroll
        for (int t = 0; t < 16; ++t) s += pred[t][r][a];
        float v = tanhf(s) * query[a];
#pragma unroll
        for (int off = 32; off; off >>= 1) v += __shfl_down(v, off, 64);
        if ((tid & 63) == 0) redr[r][(tid >> 6) & 1] = v;
    }
    if (tid < CH) amis[tid] = am[b * SS + j0 + tid];
    __syncthreads();
    if (tid < CH) {
        const float t = redr[tid][0] + redr[tid][1];
        const float e = expf(t);       // unshifted: |t| <= ~9 for this problem
        Wl[tid] = amis[tid] ? e : 0.f;
        Ews[b * SS + j0 + tid] = e;
    }
    __syncthreads();

    if (tid < HH) {
        const float cacc = fmaf(Wl[0], xs[0][tid],
                           fmaf(Wl[1], xs[1][tid],
                           fmaf(Wl[2], xs[2][tid],
                                Wl[3] * xs[3][tid])));
        Cws[(size_t)(b * NCH + c) * HH + tid] = cacc;
    }
}

// ---------------------------------------------------------------------------
// Kernel 2: 512 blocks x 256 thr, 2 output rows per block (2 blocks/CU):
//   P_i = sum_{j<=i} E[j];  d[i,j] = (j<=i && am_i && am_j) ? E[j]/P_i : 0
//   a[i,h] = am_i/P_i * ( sum_{chunks below} C[cc][h] + incremental rows )
// Critical-path order: issue the Cws prefix chain FIRST (longest latency),
// overlap the Ews shuffle-reduce under it; unroll 2 -> 16 loads in flight.
// ---------------------------------------------------------------------------
__global__ __launch_bounds__(256, 4)
void k_O(const float* __restrict__ Ews,
         const float* __restrict__ Cws,
         const int* __restrict__ am,
         const float* __restrict__ x,
         float* __restrict__ dout,
         float* __restrict__ aout) {
    const int blk = blockIdx.x;            // 0..511
    const int b   = blk >> 8;
    const int i0  = (blk & 255) << 1;      // even row base, 2 rows per block
    const int tid = threadIdx.x;           // 0..255
    const int lane = tid & 63;

    __shared__ float Es[SS];
    __shared__ float Ws[SS];
    __shared__ float red[4];
    __shared__ float Pinv[2];
    __shared__ int   amis[2];

    const float e0 = Ews[b * SS + tid];
    const float e1 = Ews[b * SS + tid + 256];
    const int  m0  = am[b * SS + tid];
    const int  m1  = am[b * SS + tid + 256];

    // ---- Cws prefix: start the long L2 latency chain immediately -----------
    const int h     = tid;                  // 256 threads == HH
    const int nfull = i0 >> 2;              // chunks strictly below i0
    const float* Cb = Cws + (size_t)b * NCH * HH + h;
    float s0 = 0.f, s1 = 0.f, s2 = 0.f, s3 = 0.f;
    float s4 = 0.f, s5 = 0.f, s6 = 0.f, s7 = 0.f;
    int cc = 0;
#pragma unroll 2
    for (; cc + 8 <= nfull; cc += 8) {
        s0 += Cb[(size_t)(cc + 0) * HH];
        s1 += Cb[(size_t)(cc + 1) * HH];
        s2 += Cb[(size_t)(cc + 2) * HH];
        s3 += Cb[(size_t)(cc + 3) * HH];
        s4 += Cb[(size_t)(cc + 4) * HH];
        s5 += Cb[(size_t)(cc + 5) * HH];
        s6 += Cb[(size_t)(cc + 6) * HH];
        s7 += Cb[(size_t)(cc + 7) * HH];
    }
    for (; cc < nfull; ++cc) s0 += Cb[(size_t)cc * HH];
    float acc = ((s0 + s1) + (s2 + s3)) + ((s4 + s5) + (s6 + s7));

    // ---- E staging + P reduce (overlaps the loads above in other waves) ----
    Es[tid] = e0;             Es[tid + 256] = e1;
    Ws[tid] = m0 ? e0 : 0.f;  Ws[tid + 256] = m1 ? e1 : 0.f;

    float p = ((tid <= i0) ? e0 : 0.f) + ((tid + 256 <= i0) ? e1 : 0.f);
#pragma unroll
    for (int off = 32; off; off >>= 1) p += __shfl_down(p, off, 64);
    if (lane == 0) red[tid >> 6] = p;
    if (tid < 2) amis[tid] = am[b * SS + i0 + tid];
    __syncthreads();
    if (tid == 0) {
        const float P0 = (red[0] + red[1]) + (red[2] + red[3]);
        const float P1 = P0 + Es[i0 + 1];
        Pinv[0] = 1.f / P0;
        Pinv[1] = 1.f / P1;
    }
    __syncthreads();

    // ---- d rows: one float4 nontemporal store per thread --------------------
    {
        const int   r  = tid >> 7;          // 0..1
        const int   jc = (tid & 127) << 2;
        const int   i  = i0 + r;
        const float pv = Pinv[r];
        const bool  on = amis[r] != 0;
        const float4 wv = *(const float4*)&Ws[jc];
        f4_t o;
        o.x = (on && jc + 0 <= i) ? wv.x * pv : 0.f;
        o.y = (on && jc + 1 <= i) ? wv.y * pv : 0.f;
        o.z = (on && jc + 2 <= i) ? wv.z * pv : 0.f;
        o.w = (on && jc + 3 <= i) ? wv.w * pv : 0.f;
        __builtin_nontemporal_store(o, (f4_t*)&dout[(size_t)(b * SS + i) * SS + jc]);
    }

    // ---- a rows: incremental rows on top of the chunk prefix ----------------
    {
        const int lo    = i0 & 3;               // 0 or 2 leftover rows
        const int jbase = nfull << 2;           // first row not covered by chunks
        const float* xb = x + ((size_t)b * SS + jbase) * HH + h;
        float av0, av1;
        if (lo) {   // block-uniform branch
            acc = fmaf(Ws[jbase + 0], xb[0 * HH], acc);
            acc = fmaf(Ws[jbase + 1], xb[1 * HH], acc);
            av0 = fmaf(Ws[i0 + 0],    xb[2 * HH], acc);
            av1 = fmaf(Ws[i0 + 1],    xb[3 * HH], av0);
        } else {
            av0 = fmaf(Ws[i0 + 0],    xb[0 * HH], acc);
            av1 = fmaf(Ws[i0 + 1],    xb[1 * HH], av0);
        }

        const size_t arow = (size_t)(b * SS + i0) * HH + h;
        __builtin_nontemporal_store(amis[0] ? av0 * Pinv[0] : 0.f, &aout[arow + 0 * HH]);
        __builtin_nontemporal_store(amis[1] ? av1 * Pinv[1] : 0.f, &aout[arow + 1 * HH]);
    }
}

// ---------------------------------------------------------------------------
extern "C" void kernel_launch(void* const* d_in, const int* in_sizes, int n_in,
                              void* d_out, int out_size, void* d_ws, size_t ws_size,
                              hipStream_t stream) {
    const float* x     = (const float*)d_in[0];
    const int*   am    = (const int*)d_in[1];
    const float* w_a   = (const float*)d_in[2];
    const float* query = (const float*)d_in[3];

    float* a_out  = (float*)d_out;                   // B*S*H
    float* d_outp = a_out + (size_t)BB * SS * HH;    // B*S*S

    float* Ews = (float*)d_ws;                       // B*S floats
    float* Cws = Ews + BB * SS;                      // B*NCH*H floats (256 KB)

    k_E<<<NBLK,       NT1, 0, stream>>>(x, am, w_a, query, Ews, Cws);
    k_O<<<BB * SS / 2, 256, 0, stream>>>(Ews, Cws, am, x, d_outp, a_out);
}